// Round 1
// 878.066 us; speedup vs baseline: 1.3192x; 1.3192x over previous
//
#include <hip/hip_runtime.h>
#include <math.h>

// Sliced Wasserstein-2: for each (b,c,p): W2^2 = mean_i (sort(X@theta_p) - sort(Y@theta_p))^2
// loss = mean_{b,c} sqrt(mean_p W2^2)
//
// R17 = R16 low ladder (a=1..11 untouched: DPP m=1/2/8, sel_ce, bpermute m=4/16/32)
// + OCCUPANCY REDESIGN: full-array LDS transposes (merge_high3, 144 KB LDS,
// 1 block/CU) replaced by split element-wise exchange stages (m=64..512)
// through a 64 KB half-buffer -> 2 blocks/CU (32 waves). High merges a=13..15
// now: exch stages (b>=11) + cross-lane b10..b5 + in-reg tail. Costs ~+20%
// VALU and more barriers; buys 2x wave concurrency so one block's barrier
// stalls are filled by the sibling block. __launch_bounds__(1024,8) pins
// VGPR<=64 so 2 blocks actually co-schedule.

namespace {
constexpr int Bb = 8, Cc = 4, Nn = 32768, Pp = 50;
constexpr int THREADS = 1024;
constexpr int VPT = 32;                    // values per thread
constexpr int SLICES = Bb * Cc * Pp;       // 1600
constexpr size_t W2_BYTES = 8192;          // w2[1600] rounded up
constexpr int LDS_FLOATS = Nn / 2;         // 16384 floats = 64 KB half-buffer
}

__device__ __forceinline__ void ce(float& a, float& b, bool up) {
  float lo = fminf(a, b);
  float hi = fmaxf(a, b);
  a = up ? lo : hi;
  b = up ? hi : lo;
}

// 2-VALU compare-select CE: keepMin ? min(v,o) : max(v,o); ties resolve
// consistently on both partners (multiset preserved).
__device__ __forceinline__ float sel_ce(float v, float o, bool keepMin) {
  return ((o < v) != keepMin) ? v : o;
}

// DPP lane move with compile-time control word.
// 0xB1 = quad_perm(1,0,3,2) = xor1; 0x4E = quad_perm(2,3,0,1) = xor2;
// 0x128 = row_ror:8 = xor8 on each 16-lane row.
template<int CTRL>
__device__ __forceinline__ float dpp_move(float x) {
  int i = __builtin_amdgcn_update_dpp(0, __float_as_int(x), CTRL, 0xF, 0xF, true);
  return __int_as_float(i);
}

// cross-lane CE stage with xor-mask M (M=1,2,8 via DPP; M=4,16,32 via bpermute)
template<int M>
__device__ __forceinline__ void stage_xlane(float v[VPT], int tid, bool up) {
  const bool keepMin = (up == ((tid & M) == 0));
  if constexpr (M == 1 || M == 2 || M == 8) {
    constexpr int ctrl = (M == 1) ? 0xB1 : (M == 2) ? 0x4E : 0x128;
#pragma unroll
    for (int r = 0; r < VPT; r++) {
      float o = dpp_move<ctrl>(v[r]);
      v[r] = sel_ce(v[r], o, keepMin);
    }
  } else {
    const int addr = (((tid & 63) ^ M) << 2);
#pragma unroll
    for (int r = 0; r < VPT; r++) {
      float o = __int_as_float(
          __builtin_amdgcn_ds_bpermute(addr, __float_as_int(v[r])));
      v[r] = sel_ce(v[r], o, keepMin);
    }
  }
}

// 5-stage in-register network on the reg-index bits (j=16..1), direction
// uniform per thread via sign-flip trick.
__device__ __forceinline__ void tail_inreg(float v[VPT], bool up) {
  const unsigned flip = up ? 0u : 0x80000000u;
#pragma unroll
  for (int r = 0; r < VPT; r++)
    v[r] = __int_as_float(__float_as_int(v[r]) ^ flip);
#pragma unroll
  for (int j = 16; j > 0; j >>= 1) {
#pragma unroll
    for (int r = 0; r < VPT; r++) {
      if (!(r & j)) {
        float a = v[r], b = v[r | j];
        v[r] = fminf(a, b);
        v[r | j] = fmaxf(a, b);
      }
    }
  }
#pragma unroll
  for (int r = 0; r < VPT; r++)
    v[r] = __int_as_float(__float_as_int(v[r]) ^ flip);
}

// wave-local cross stages (m = MTOP..1) + tail, for merge k = 2^A (A<=15)
template<int A, int MTOP>
__device__ __forceinline__ void wave_stages_and_tail(float v[VPT], int tid) {
  const bool up = ((tid & (1 << (A - 5))) == 0);
  if constexpr (MTOP >= 32) stage_xlane<32>(v, tid, up);
  if constexpr (MTOP >= 16) stage_xlane<16>(v, tid, up);
  if constexpr (MTOP >= 8)  stage_xlane<8>(v, tid, up);
  if constexpr (MTOP >= 4)  stage_xlane<4>(v, tid, up);
  if constexpr (MTOP >= 2)  stage_xlane<2>(v, tid, up);
  if constexpr (MTOP >= 1)  stage_xlane<1>(v, tid, up);
  tail_inreg(v, up);
}

// Wave-crossing exchange stage (xor-mask m>=64 on tid), element-wise,
// SPLIT through the 16K-float half buffer in two 16-reg rounds so LDS
// stays at 64 KB (-> 2 blocks/CU). Column layout s[r*1024+tid]: 2-way
// bank aliasing only (free). Safe split: round-2 writes happen after the
// barrier that ends round-1 reads; v[] is preserved across reads (CE is
// element-wise, no layout change).
__device__ __forceinline__ void stage_exch(float v[VPT], float* s, int tid,
                                           int m, bool up) {
  const bool keepMin = (up == ((tid & m) == 0));
  const int pt = tid ^ m;
#pragma unroll
  for (int h = 0; h < 2; h++) {
    __syncthreads();                  // prior users of s must finish
#pragma unroll
    for (int r = 0; r < VPT / 2; r++)
      s[r * THREADS + tid] = v[h * (VPT / 2) + r];
    __syncthreads();
#pragma unroll
    for (int r = 0; r < VPT / 2; r++) {
      float o = s[r * THREADS + pt];
      v[h * (VPT / 2) + r] = sel_ce(v[h * (VPT / 2) + r], o, keepMin);
    }
  }
}

// Full distributed bitonic sort: rank of v[r] on thread tid is tid*32 + r.
__device__ __forceinline__ void sort_dist(float v[VPT], float* s, int tid) {
  // merges a=1..4 (k=2..16): in-register, compile-time directions
#pragma unroll
  for (int k = 2; k <= 16; k <<= 1) {
#pragma unroll
    for (int j = k >> 1; j > 0; j >>= 1) {
#pragma unroll
      for (int r = 0; r < VPT; r++)
        if (!(r & j)) ce(v[r], v[r | j], (r & k) == 0);
    }
  }
  // a=5 (k=32): dir = tid bit0, all stages in-register
  tail_inreg(v, (tid & 1) == 0);
  // a=6..11: wave-local exchanges + tail
  wave_stages_and_tail<6, 1>(v, tid);
  wave_stages_and_tail<7, 2>(v, tid);
  wave_stages_and_tail<8, 4>(v, tid);
  wave_stages_and_tail<9, 8>(v, tid);
  wave_stages_and_tail<10, 16>(v, tid);
  wave_stages_and_tail<11, 32>(v, tid);
  // a=12: one wave-crossing stage (b11 -> m=64), then wave-local
  stage_exch(v, s, tid, 64, (tid & 128) == 0);
  wave_stages_and_tail<12, 32>(v, tid);
  // a=13: b12,b11 wave-crossing, then wave-local (dir = tid bit 8)
  {
    const bool u = (tid & 256) == 0;
    stage_exch(v, s, tid, 128, u);
    stage_exch(v, s, tid, 64, u);
  }
  wave_stages_and_tail<13, 32>(v, tid);
  // a=14: b13..b11 wave-crossing (dir = tid bit 9)
  {
    const bool u = (tid & 512) == 0;
    stage_exch(v, s, tid, 256, u);
    stage_exch(v, s, tid, 128, u);
    stage_exch(v, s, tid, 64, u);
  }
  wave_stages_and_tail<14, 32>(v, tid);
  // a=15 (final, all ascending): b14..b11 wave-crossing
  stage_exch(v, s, tid, 512, true);
  stage_exch(v, s, tid, 256, true);
  stage_exch(v, s, tid, 128, true);
  stage_exch(v, s, tid, 64, true);
  wave_stages_and_tail<15, 32>(v, tid);
}

__device__ __forceinline__ void project_slice(const float4* base, float t0, float t1,
                                              int tid, float v[VPT]) {
#pragma unroll
  for (int q = 0; q < VPT / 2; q++) {
    float4 u = base[tid * (VPT / 2) + q];
    v[2 * q]     = fmaf(u.x, t0, u.y * t1);
    v[2 * q + 1] = fmaf(u.z, t0, u.w * t1);
  }
}

// ---- kernel A: sort X slice, stage sorted run in scratch ----
extern "C" __global__ void __launch_bounds__(THREADS, 8)
swd_sortx(const float* __restrict__ x, const float* __restrict__ proj,
          float* __restrict__ xs, int slice_base) {
  extern __shared__ float s[];
  const int slice = slice_base + blockIdx.x;
  const int p  = slice % Pp;
  const int bc = slice / Pp;
  const int tid = threadIdx.x;
  const float t0 = proj[2 * p];
  const float t1 = proj[2 * p + 1];
  float v[VPT];
  project_slice((const float4*)(x + (size_t)bc * Nn * 2), t0, t1, tid, v);
  sort_dist(v, s, tid);
  float4* o = (float4*)(xs + (size_t)blockIdx.x * Nn + tid * VPT);
#pragma unroll
  for (int q = 0; q < VPT / 4; q++)
    o[q] = make_float4(v[4 * q], v[4 * q + 1], v[4 * q + 2], v[4 * q + 3]);
}

// ---- kernel B: sort Y slice, diff against staged sorted X, reduce ----
extern "C" __global__ void __launch_bounds__(THREADS, 8)
swd_sorty(const float* __restrict__ y, const float* __restrict__ proj,
          const float* __restrict__ xs, float* __restrict__ w2, int slice_base) {
  extern __shared__ float s[];
  __shared__ float wsum[THREADS / 64];
  const int slice = slice_base + blockIdx.x;
  const int p  = slice % Pp;
  const int bc = slice / Pp;
  const int tid = threadIdx.x;
  const float t0 = proj[2 * p];
  const float t1 = proj[2 * p + 1];
  float v[VPT];
  project_slice((const float4*)(y + (size_t)bc * Nn * 2), t0, t1, tid, v);
  sort_dist(v, s, tid);

  const float4* xr = (const float4*)(xs + (size_t)blockIdx.x * Nn + tid * VPT);
  float acc = 0.f;
#pragma unroll
  for (int q = 0; q < VPT / 4; q++) {
    float4 u = xr[q];
    float d0 = u.x - v[4 * q];
    float d1 = u.y - v[4 * q + 1];
    float d2 = u.z - v[4 * q + 2];
    float d3 = u.w - v[4 * q + 3];
    acc = fmaf(d0, d0, acc);
    acc = fmaf(d1, d1, acc);
    acc = fmaf(d2, d2, acc);
    acc = fmaf(d3, d3, acc);
  }
#pragma unroll
  for (int off = 32; off > 0; off >>= 1)
    acc += __shfl_down(acc, off, 64);
  if ((tid & 63) == 0) wsum[tid >> 6] = acc;
  __syncthreads();
  if (tid == 0) {
    float t = 0.f;
#pragma unroll
    for (int w = 0; w < THREADS / 64; w++) t += wsum[w];
    w2[slice] = t * (1.0f / Nn);
  }
}

extern "C" __global__ void swd_final(const float* __restrict__ w2,
                                     float* __restrict__ out) {
  __shared__ float sred[Bb * Cc];
  int t = threadIdx.x;
  if (t < Bb * Cc) {
    float sum = 0.f;
    for (int p = 0; p < Pp; p++) sum += w2[t * Pp + p];
    sred[t] = sqrtf(sum * (1.0f / Pp));
  }
  __syncthreads();
  if (t == 0) {
    float a = 0.f;
    for (int i = 0; i < Bb * Cc; i++) a += sred[i];
    out[0] = a * (1.0f / (Bb * Cc));
  }
}

extern "C" void kernel_launch(void* const* d_in, const int* in_sizes, int n_in,
                              void* d_out, int out_size, void* d_ws, size_t ws_size,
                              hipStream_t stream) {
  const float* x    = (const float*)d_in[0];
  const float* y    = (const float*)d_in[1];
  const float* proj = (const float*)d_in[2];
  float* w2  = (float*)d_ws;                       // first 8KB of scratch
  float* xs  = (float*)((char*)d_ws + W2_BYTES);   // sorted-X staging
  float* out = (float*)d_out;

  const size_t lds = (size_t)LDS_FLOATS * sizeof(float);  // 64 KB
  (void)hipFuncSetAttribute((const void*)swd_sortx,
                            hipFuncAttributeMaxDynamicSharedMemorySize, (int)lds);
  (void)hipFuncSetAttribute((const void*)swd_sorty,
                            hipFuncAttributeMaxDynamicSharedMemorySize, (int)lds);

  const size_t slice_bytes = (size_t)Nn * sizeof(float);
  const size_t avail = ws_size > W2_BYTES ? ws_size - W2_BYTES : 0;
  int chunk = (int)(avail / slice_bytes);
  if (chunk > SLICES) chunk = SLICES;
  if (chunk < 1) chunk = 1;

  for (int base = 0; base < SLICES; base += chunk) {
    int n = SLICES - base < chunk ? SLICES - base : chunk;
    hipLaunchKernelGGL(swd_sortx, dim3(n), dim3(THREADS), lds, stream,
                       x, proj, xs, base);
    hipLaunchKernelGGL(swd_sorty, dim3(n), dim3(THREADS), lds, stream,
                       y, proj, xs, w2, base);
  }
  hipLaunchKernelGGL(swd_final, dim3(1), dim3(64), 0, stream, w2, out);
}

// Round 2
// 871.091 us; speedup vs baseline: 1.3298x; 1.0080x over previous
//
#include <hip/hip_runtime.h>
#include <math.h>

// Sliced Wasserstein-2: for each (b,c,p): W2^2 = mean_i (sort(X@theta_p) - sort(Y@theta_p))^2
// loss = mean_{b,c} sqrt(mean_p W2^2)
//
// R18 = R17 (split exch stages, 64KB LDS, 2 blocks/CU) + GRID-TAIL FIX:
// grid 1600 over 512 slots = 3.125 rounds -> 78% util was the dominant loss
// (VALUBusy/Occupancy ~ 97%: VALU saturated while resident). New pipeline:
//   1) swd_halfsort: 6400 blocks x 512 thr, each bitonic-sorts a 16K half
//      (X and Y, half 0 asc / half 1 desc -> concatenation is bitonic).
//      Merges a=1..14 = 87.5% of stage work at 89.3% util (6400/1024 slots).
//   2) swd_mergex: 1600 blocks x 1024 thr, final 32K merge (a=15) of X,
//      in-place in workspace. ~BW-floor.
//   3) swd_mergey: same for Y + diff vs sorted X + reduce to w2.
// Sorting is a permutation -> output bit-identical to R17 (absmax 0).
// Needs 400MB workspace; falls back to R17 kernels verbatim if ws smaller.

namespace {
constexpr int Bb = 8, Cc = 4, Nn = 32768, Pp = 50;
constexpr int T1024 = 1024, T512 = 512;
constexpr int VPT = 32;                    // values per thread
constexpr int SLICES = Bb * Cc * Pp;       // 1600
constexpr size_t W2_BYTES = 8192;          // w2[1600] rounded up
constexpr int LDS_FLOATS_FULL = Nn / 2;    // 16384 floats = 64 KB (1024-thr kernels)
constexpr int LDS_FLOATS_HALF = Nn / 4;    // 8192 floats  = 32 KB (512-thr halfsort)
}

__device__ __forceinline__ void ce(float& a, float& b, bool up) {
  float lo = fminf(a, b);
  float hi = fmaxf(a, b);
  a = up ? lo : hi;
  b = up ? hi : lo;
}

// 2-VALU compare-select CE: keepMin ? min(v,o) : max(v,o); ties resolve
// consistently on both partners (multiset preserved).
__device__ __forceinline__ float sel_ce(float v, float o, bool keepMin) {
  return ((o < v) != keepMin) ? v : o;
}

// DPP lane move with compile-time control word.
// 0xB1 = quad_perm(1,0,3,2) = xor1; 0x4E = quad_perm(2,3,0,1) = xor2;
// 0x128 = row_ror:8 = xor8 on each 16-lane row.
template<int CTRL>
__device__ __forceinline__ float dpp_move(float x) {
  int i = __builtin_amdgcn_update_dpp(0, __float_as_int(x), CTRL, 0xF, 0xF, true);
  return __int_as_float(i);
}

// cross-lane CE stage with xor-mask M (M=1,2,8 via DPP; M=4,16,32 via bpermute)
template<int M>
__device__ __forceinline__ void stage_xlane(float v[VPT], int tid, bool up) {
  const bool keepMin = (up == ((tid & M) == 0));
  if constexpr (M == 1 || M == 2 || M == 8) {
    constexpr int ctrl = (M == 1) ? 0xB1 : (M == 2) ? 0x4E : 0x128;
#pragma unroll
    for (int r = 0; r < VPT; r++) {
      float o = dpp_move<ctrl>(v[r]);
      v[r] = sel_ce(v[r], o, keepMin);
    }
  } else {
    const int addr = (((tid & 63) ^ M) << 2);
#pragma unroll
    for (int r = 0; r < VPT; r++) {
      float o = __int_as_float(
          __builtin_amdgcn_ds_bpermute(addr, __float_as_int(v[r])));
      v[r] = sel_ce(v[r], o, keepMin);
    }
  }
}

// 5-stage in-register network on the reg-index bits (j=16..1), direction
// uniform per thread via sign-flip trick.
__device__ __forceinline__ void tail_inreg(float v[VPT], bool up) {
  const unsigned flip = up ? 0u : 0x80000000u;
#pragma unroll
  for (int r = 0; r < VPT; r++)
    v[r] = __int_as_float(__float_as_int(v[r]) ^ flip);
#pragma unroll
  for (int j = 16; j > 0; j >>= 1) {
#pragma unroll
    for (int r = 0; r < VPT; r++) {
      if (!(r & j)) {
        float a = v[r], b = v[r | j];
        v[r] = fminf(a, b);
        v[r | j] = fmaxf(a, b);
      }
    }
  }
#pragma unroll
  for (int r = 0; r < VPT; r++)
    v[r] = __int_as_float(__float_as_int(v[r]) ^ flip);
}

// wave-local cross stages (m = MTOP..1) + tail, explicit direction
template<int MTOP>
__device__ __forceinline__ void wave_ladder_tail_up(float v[VPT], int tid, bool up) {
  if constexpr (MTOP >= 32) stage_xlane<32>(v, tid, up);
  if constexpr (MTOP >= 16) stage_xlane<16>(v, tid, up);
  if constexpr (MTOP >= 8)  stage_xlane<8>(v, tid, up);
  if constexpr (MTOP >= 4)  stage_xlane<4>(v, tid, up);
  if constexpr (MTOP >= 2)  stage_xlane<2>(v, tid, up);
  if constexpr (MTOP >= 1)  stage_xlane<1>(v, tid, up);
  tail_inreg(v, up);
}

// direction from bit A of global rank (= tid bit A-5)
template<int A, int MTOP>
__device__ __forceinline__ void wave_stages_and_tail(float v[VPT], int tid) {
  wave_ladder_tail_up<MTOP>(v, tid, ((tid & (1 << (A - 5))) == 0));
}

// Wave-crossing exchange stage (xor-mask m>=64 on tid), element-wise,
// SPLIT through a half-size buffer in two 16-reg rounds. Column layout
// s[r*NT+tid]: conflict-free. Safe split: round-2 writes happen after the
// barrier that ends round-1 reads; v[] is preserved across reads.
template<int NT>
__device__ __forceinline__ void stage_exch(float v[VPT], float* s, int tid,
                                           int m, bool up) {
  const bool keepMin = (up == ((tid & m) == 0));
  const int pt = tid ^ m;
#pragma unroll
  for (int h = 0; h < 2; h++) {
    __syncthreads();                  // prior users of s must finish
#pragma unroll
    for (int r = 0; r < VPT / 2; r++)
      s[r * NT + tid] = v[h * (VPT / 2) + r];
    __syncthreads();
#pragma unroll
    for (int r = 0; r < VPT / 2; r++) {
      float o = s[r * NT + pt];
      v[h * (VPT / 2) + r] = sel_ce(v[h * (VPT / 2) + r], o, keepMin);
    }
  }
}

// in-register merges a=1..4 (k=2..16), compile-time directions
__device__ __forceinline__ void low_merges_inreg(float v[VPT]) {
#pragma unroll
  for (int k = 2; k <= 16; k <<= 1) {
#pragma unroll
    for (int j = k >> 1; j > 0; j >>= 1) {
#pragma unroll
      for (int r = 0; r < VPT; r++)
        if (!(r & j)) ce(v[r], v[r | j], (r & k) == 0);
    }
  }
}

// ---- 16K bitonic sort, 512 threads, final direction uh (true=asc) ----
__device__ __forceinline__ void sort_16k(float v[VPT], float* s, int tid, bool uh) {
  low_merges_inreg(v);
  tail_inreg(v, (tid & 1) == 0);          // a=5
  wave_stages_and_tail<6, 1>(v, tid);
  wave_stages_and_tail<7, 2>(v, tid);
  wave_stages_and_tail<8, 4>(v, tid);
  wave_stages_and_tail<9, 8>(v, tid);
  wave_stages_and_tail<10, 16>(v, tid);
  wave_stages_and_tail<11, 32>(v, tid);
  // a=12: one wave-crossing stage (m=64), dir = tid bit 7
  stage_exch<T512>(v, s, tid, 64, (tid & 128) == 0);
  wave_stages_and_tail<12, 32>(v, tid);
  // a=13: m=128,64, dir = tid bit 8
  {
    const bool u = (tid & 256) == 0;
    stage_exch<T512>(v, s, tid, 128, u);
    stage_exch<T512>(v, s, tid, 64, u);
  }
  wave_stages_and_tail<13, 32>(v, tid);
  // a=14 (final): dir = uh uniformly
  stage_exch<T512>(v, s, tid, 256, uh);
  stage_exch<T512>(v, s, tid, 128, uh);
  stage_exch<T512>(v, s, tid, 64, uh);
  wave_ladder_tail_up<32>(v, tid, uh);
}

// ---- final 32K bitonic merge (a=15, all ascending), 1024 threads ----
__device__ __forceinline__ void merge_32k_final(float v[VPT], float* s, int tid) {
  stage_exch<T1024>(v, s, tid, 512, true);
  stage_exch<T1024>(v, s, tid, 256, true);
  stage_exch<T1024>(v, s, tid, 128, true);
  stage_exch<T1024>(v, s, tid, 64, true);
  wave_ladder_tail_up<32>(v, tid, true);
}

// ---- full 32K distributed bitonic sort, 1024 threads (legacy path) ----
__device__ __forceinline__ void sort_dist(float v[VPT], float* s, int tid) {
  low_merges_inreg(v);
  tail_inreg(v, (tid & 1) == 0);          // a=5
  wave_stages_and_tail<6, 1>(v, tid);
  wave_stages_and_tail<7, 2>(v, tid);
  wave_stages_and_tail<8, 4>(v, tid);
  wave_stages_and_tail<9, 8>(v, tid);
  wave_stages_and_tail<10, 16>(v, tid);
  wave_stages_and_tail<11, 32>(v, tid);
  stage_exch<T1024>(v, s, tid, 64, (tid & 128) == 0);
  wave_stages_and_tail<12, 32>(v, tid);
  {
    const bool u = (tid & 256) == 0;
    stage_exch<T1024>(v, s, tid, 128, u);
    stage_exch<T1024>(v, s, tid, 64, u);
  }
  wave_stages_and_tail<13, 32>(v, tid);
  {
    const bool u = (tid & 512) == 0;
    stage_exch<T1024>(v, s, tid, 256, u);
    stage_exch<T1024>(v, s, tid, 128, u);
    stage_exch<T1024>(v, s, tid, 64, u);
  }
  wave_stages_and_tail<14, 32>(v, tid);
  merge_32k_final(v, s, tid);
}

__device__ __forceinline__ void project_slice(const float4* base, float t0, float t1,
                                              int tid, float v[VPT]) {
#pragma unroll
  for (int q = 0; q < VPT / 2; q++) {
    float4 u = base[tid * (VPT / 2) + q];
    v[2 * q]     = fmaf(u.x, t0, u.y * t1);
    v[2 * q + 1] = fmaf(u.z, t0, u.w * t1);
  }
}

// ==================== pipeline kernels (R18) ====================

// item = (slice_local<<2) | (arr<<1) | half;  arr: 0=X 1=Y
extern "C" __global__ void __launch_bounds__(T512, 8)
swd_halfsort(const float* __restrict__ x, const float* __restrict__ y,
             const float* __restrict__ proj, float* __restrict__ hs,
             int slice_base) {
  extern __shared__ float s[];
  const int item = blockIdx.x;
  const int sl   = item >> 2;
  const int arr  = (item >> 1) & 1;
  const int h    = item & 1;
  const int slice = slice_base + sl;
  const int p  = slice % Pp;
  const int bc = slice / Pp;
  const int tid = threadIdx.x;
  const float t0 = proj[2 * p];
  const float t1 = proj[2 * p + 1];
  const float* src = arr ? y : x;
  // half h covers points [h*16384, (h+1)*16384): offset h*Nn floats (D=2)
  const float4* base = (const float4*)(src + (size_t)bc * Nn * 2 + (size_t)h * Nn);
  float v[VPT];
  project_slice(base, t0, t1, tid, v);
  sort_16k(v, s, tid, h == 0);            // half 0 asc, half 1 desc -> bitonic
  float4* o = (float4*)(hs + ((size_t)sl * 2 + arr) * Nn + (size_t)h * (Nn / 2)
                        + (size_t)tid * VPT);
#pragma unroll
  for (int q = 0; q < VPT / 4; q++)
    o[q] = make_float4(v[4 * q], v[4 * q + 1], v[4 * q + 2], v[4 * q + 3]);
}

// final merge of X, in place in hs
extern "C" __global__ void __launch_bounds__(T1024, 8)
swd_mergex(float* __restrict__ hs) {
  extern __shared__ float s[];
  const int sl = blockIdx.x;
  const int tid = threadIdx.x;
  float* g = hs + (size_t)sl * 2 * Nn;
  float v[VPT];
  const float4* gi = (const float4*)(g + (size_t)tid * VPT);
#pragma unroll
  for (int q = 0; q < VPT / 4; q++) {
    float4 u = gi[q];
    v[4 * q] = u.x; v[4 * q + 1] = u.y; v[4 * q + 2] = u.z; v[4 * q + 3] = u.w;
  }
  merge_32k_final(v, s, tid);
  float4* go = (float4*)(g + (size_t)tid * VPT);
#pragma unroll
  for (int q = 0; q < VPT / 4; q++)
    go[q] = make_float4(v[4 * q], v[4 * q + 1], v[4 * q + 2], v[4 * q + 3]);
}

// final merge of Y + diff against sorted X + reduce
extern "C" __global__ void __launch_bounds__(T1024, 8)
swd_mergey(const float* __restrict__ hs, float* __restrict__ w2, int slice_base) {
  extern __shared__ float s[];
  __shared__ float wsum[T1024 / 64];
  const int sl = blockIdx.x;
  const int slice = slice_base + sl;
  const int tid = threadIdx.x;
  const float* gy = hs + ((size_t)sl * 2 + 1) * Nn;
  const float* gx = hs + (size_t)sl * 2 * Nn;
  float v[VPT];
  const float4* gi = (const float4*)(gy + (size_t)tid * VPT);
#pragma unroll
  for (int q = 0; q < VPT / 4; q++) {
    float4 u = gi[q];
    v[4 * q] = u.x; v[4 * q + 1] = u.y; v[4 * q + 2] = u.z; v[4 * q + 3] = u.w;
  }
  merge_32k_final(v, s, tid);

  const float4* xr = (const float4*)(gx + (size_t)tid * VPT);
  float acc = 0.f;
#pragma unroll
  for (int q = 0; q < VPT / 4; q++) {
    float4 u = xr[q];
    float d0 = u.x - v[4 * q];
    float d1 = u.y - v[4 * q + 1];
    float d2 = u.z - v[4 * q + 2];
    float d3 = u.w - v[4 * q + 3];
    acc = fmaf(d0, d0, acc);
    acc = fmaf(d1, d1, acc);
    acc = fmaf(d2, d2, acc);
    acc = fmaf(d3, d3, acc);
  }
#pragma unroll
  for (int off = 32; off > 0; off >>= 1)
    acc += __shfl_down(acc, off, 64);
  if ((tid & 63) == 0) wsum[tid >> 6] = acc;
  __syncthreads();
  if (tid == 0) {
    float t = 0.f;
#pragma unroll
    for (int w = 0; w < T1024 / 64; w++) t += wsum[w];
    w2[slice] = t * (1.0f / Nn);
  }
}

// ==================== legacy kernels (R17 fallback) ====================

extern "C" __global__ void __launch_bounds__(T1024, 8)
swd_sortx(const float* __restrict__ x, const float* __restrict__ proj,
          float* __restrict__ xs, int slice_base) {
  extern __shared__ float s[];
  const int slice = slice_base + blockIdx.x;
  const int p  = slice % Pp;
  const int bc = slice / Pp;
  const int tid = threadIdx.x;
  const float t0 = proj[2 * p];
  const float t1 = proj[2 * p + 1];
  float v[VPT];
  project_slice((const float4*)(x + (size_t)bc * Nn * 2), t0, t1, tid, v);
  sort_dist(v, s, tid);
  float4* o = (float4*)(xs + (size_t)blockIdx.x * Nn + tid * VPT);
#pragma unroll
  for (int q = 0; q < VPT / 4; q++)
    o[q] = make_float4(v[4 * q], v[4 * q + 1], v[4 * q + 2], v[4 * q + 3]);
}

extern "C" __global__ void __launch_bounds__(T1024, 8)
swd_sorty(const float* __restrict__ y, const float* __restrict__ proj,
          const float* __restrict__ xs, float* __restrict__ w2, int slice_base) {
  extern __shared__ float s[];
  __shared__ float wsum[T1024 / 64];
  const int slice = slice_base + blockIdx.x;
  const int p  = slice % Pp;
  const int bc = slice / Pp;
  const int tid = threadIdx.x;
  const float t0 = proj[2 * p];
  const float t1 = proj[2 * p + 1];
  float v[VPT];
  project_slice((const float4*)(y + (size_t)bc * Nn * 2), t0, t1, tid, v);
  sort_dist(v, s, tid);

  const float4* xr = (const float4*)(xs + (size_t)blockIdx.x * Nn + tid * VPT);
  float acc = 0.f;
#pragma unroll
  for (int q = 0; q < VPT / 4; q++) {
    float4 u = xr[q];
    float d0 = u.x - v[4 * q];
    float d1 = u.y - v[4 * q + 1];
    float d2 = u.z - v[4 * q + 2];
    float d3 = u.w - v[4 * q + 3];
    acc = fmaf(d0, d0, acc);
    acc = fmaf(d1, d1, acc);
    acc = fmaf(d2, d2, acc);
    acc = fmaf(d3, d3, acc);
  }
#pragma unroll
  for (int off = 32; off > 0; off >>= 1)
    acc += __shfl_down(acc, off, 64);
  if ((tid & 63) == 0) wsum[tid >> 6] = acc;
  __syncthreads();
  if (tid == 0) {
    float t = 0.f;
#pragma unroll
    for (int w = 0; w < T1024 / 64; w++) t += wsum[w];
    w2[slice] = t * (1.0f / Nn);
  }
}

extern "C" __global__ void swd_final(const float* __restrict__ w2,
                                     float* __restrict__ out) {
  __shared__ float sred[Bb * Cc];
  int t = threadIdx.x;
  if (t < Bb * Cc) {
    float sum = 0.f;
    for (int p = 0; p < Pp; p++) sum += w2[t * Pp + p];
    sred[t] = sqrtf(sum * (1.0f / Pp));
  }
  __syncthreads();
  if (t == 0) {
    float a = 0.f;
    for (int i = 0; i < Bb * Cc; i++) a += sred[i];
    out[0] = a * (1.0f / (Bb * Cc));
  }
}

extern "C" void kernel_launch(void* const* d_in, const int* in_sizes, int n_in,
                              void* d_out, int out_size, void* d_ws, size_t ws_size,
                              hipStream_t stream) {
  const float* x    = (const float*)d_in[0];
  const float* y    = (const float*)d_in[1];
  const float* proj = (const float*)d_in[2];
  float* w2  = (float*)d_ws;                       // first 8KB of scratch
  float* hs  = (float*)((char*)d_ws + W2_BYTES);   // staging (halves / sorted)
  float* out = (float*)d_out;

  const size_t lds_full = (size_t)LDS_FLOATS_FULL * sizeof(float);  // 64 KB
  const size_t lds_half = (size_t)LDS_FLOATS_HALF * sizeof(float);  // 32 KB
  (void)hipFuncSetAttribute((const void*)swd_halfsort,
                            hipFuncAttributeMaxDynamicSharedMemorySize, (int)lds_half);
  (void)hipFuncSetAttribute((const void*)swd_mergex,
                            hipFuncAttributeMaxDynamicSharedMemorySize, (int)lds_full);
  (void)hipFuncSetAttribute((const void*)swd_mergey,
                            hipFuncAttributeMaxDynamicSharedMemorySize, (int)lds_full);
  (void)hipFuncSetAttribute((const void*)swd_sortx,
                            hipFuncAttributeMaxDynamicSharedMemorySize, (int)lds_full);
  (void)hipFuncSetAttribute((const void*)swd_sorty,
                            hipFuncAttributeMaxDynamicSharedMemorySize, (int)lds_full);

  const size_t avail = ws_size > W2_BYTES ? ws_size - W2_BYTES : 0;
  const size_t per_slice_pipe = (size_t)2 * Nn * sizeof(float);   // 256 KB (X+Y)

  if (avail >= (size_t)SLICES * per_slice_pipe) {
    // ---- R18 pipeline: full workspace, single pass ----
    hipLaunchKernelGGL(swd_halfsort, dim3(SLICES * 4), dim3(T512), lds_half,
                       stream, x, y, proj, hs, 0);
    hipLaunchKernelGGL(swd_mergex, dim3(SLICES), dim3(T1024), lds_full,
                       stream, hs);
    hipLaunchKernelGGL(swd_mergey, dim3(SLICES), dim3(T1024), lds_full,
                       stream, hs, w2, 0);
  } else {
    // ---- legacy R17 path (chunked monolithic sorts) ----
    float* xs = hs;
    const size_t slice_bytes = (size_t)Nn * sizeof(float);
    int chunk = (int)(avail / slice_bytes);
    if (chunk > SLICES) chunk = SLICES;
    if (chunk < 1) chunk = 1;
    for (int base = 0; base < SLICES; base += chunk) {
      int n = SLICES - base < chunk ? SLICES - base : chunk;
      hipLaunchKernelGGL(swd_sortx, dim3(n), dim3(T1024), lds_full, stream,
                         x, proj, xs, base);
      hipLaunchKernelGGL(swd_sorty, dim3(n), dim3(T1024), lds_full, stream,
                         y, proj, xs, w2, base);
    }
  }
  hipLaunchKernelGGL(swd_final, dim3(1), dim3(64), 0, stream, w2, out);
}